// Round 4
// baseline (3597.852 us; speedup 1.0000x reference)
//
#include <hip/hip_runtime.h>
#include <hip/hip_bf16.h>

#define Bb 32
#define Tt 512
#define Ii 256
#define Hh 512
#define Oo 128
#define NG 8    // workgroups per direction in recurrence

using bf16x8 = __attribute__((ext_vector_type(8))) __bf16;
using f32x4  = __attribute__((ext_vector_type(4))) float;

__device__ __forceinline__ bf16x8 f32x8_to_bf16(const float* p) {
    const float4 u = *reinterpret_cast<const float4*>(p);
    const float4 v = *reinterpret_cast<const float4*>(p + 4);
    bf16x8 r;
    r[0] = (__bf16)u.x; r[1] = (__bf16)u.y; r[2] = (__bf16)u.z; r[3] = (__bf16)u.w;
    r[4] = (__bf16)v.x; r[5] = (__bf16)v.y; r[6] = (__bf16)v.z; r[7] = (__bf16)v.w;
    return r;
}

__device__ __forceinline__ float sigm(float x) { return 1.f / (1.f + __expf(-x)); }
// tanh(x) = 1 - 2/(e^{2x}+1); saturates correctly for large |x| with v_exp_f32
__device__ __forceinline__ float tanh_fast(float x) {
    const float e = __expf(2.f * x);
    return 1.f - 2.f / (e + 1.f);
}
__device__ __forceinline__ unsigned short bfbits(float x) {
    return __builtin_bit_cast(unsigned short, (__bf16)x);
}
__device__ __forceinline__ float bsel(uint2 u, int j) {   // j compile-time
    const unsigned w = (j & 2) ? u.y : u.x;
    return __builtin_bit_cast(float, (j & 1) ? (w & 0xffff0000u) : (w << 16));
}

// ---------------- setup: zero flags, build initial h (fwd=0, bwd=bh0) -------
__global__ void k_setup(const float* __restrict__ bh0,
                        __bf16* __restrict__ hinit, int* __restrict__ flags) {
    const int tid = blockIdx.x * 256 + threadIdx.x;
    if (tid < 128) flags[tid] = 0;
    if (tid < Bb * Hh) {
        hinit[tid] = (__bf16)0.f;
        hinit[Bb * Hh + tid] = (__bf16)bh0[tid & (Hh - 1)];
    }
}

// ---------------- xproj = x @ Wx^T + b  -> [T][B][4H] bf16 -------------------
__global__ __launch_bounds__(256) void k_xproj(
    const float* __restrict__ x,
    const float* __restrict__ Wf, const float* __restrict__ bf_,
    const float* __restrict__ Wi, const float* __restrict__ bi_,
    const float* __restrict__ Wo, const float* __restrict__ bo_,
    const float* __restrict__ Wc, const float* __restrict__ bc_,
    __bf16* __restrict__ xproj)
{
    const int wgM = blockIdx.x;           // 0..255  (64 rows each)
    const int wgN = blockIdx.y;           // 0..15   (128 cols each)
    const int tid = threadIdx.x;
    const int wave = tid >> 6, lane = tid & 63;
    const int mw = wave >> 1, nw = wave & 1;
    const int l15 = lane & 15, lhi = lane >> 4;

    const int gamma = wgN >> 2;           // whole wg in one gate (128 | 512)
    const float* W    = (gamma == 0) ? Wf : (gamma == 1) ? Wi : (gamma == 2) ? Wo : Wc;
    const float* bptr = (gamma == 0) ? bf_ : (gamma == 1) ? bi_ : (gamma == 2) ? bo_ : bc_;

    f32x4 acc[2][4];
#pragma unroll
    for (int m = 0; m < 2; m++)
#pragma unroll
        for (int n = 0; n < 4; n++) acc[m][n] = f32x4{0.f, 0.f, 0.f, 0.f};

    const int rowbase = wgM * 64 + mw * 32;
    const int colbase = wgN * 128 + nw * 64;

#pragma unroll
    for (int kk = 0; kk < 8; ++kk) {
        const int k0 = kk * 32 + lhi * 8;
        bf16x8 a[2], b[4];
#pragma unroll
        for (int m = 0; m < 2; m++) {
            const int r = rowbase + m * 16 + l15;        // x row = b*T + t
            a[m] = f32x8_to_bf16(x + (long)r * Ii + k0);
        }
#pragma unroll
        for (int n = 0; n < 4; n++) {
            const int g = colbase + n * 16 + l15;
            b[n] = f32x8_to_bf16(W + (long)(g & 511) * 768 + k0);
        }
#pragma unroll
        for (int m = 0; m < 2; m++)
#pragma unroll
            for (int n = 0; n < 4; n++)
                acc[m][n] = __builtin_amdgcn_mfma_f32_16x16x32_bf16(a[m], b[n], acc[m][n], 0, 0, 0);
    }

#pragma unroll
    for (int m = 0; m < 2; m++)
#pragma unroll
        for (int n = 0; n < 4; n++) {
            const int g = colbase + n * 16 + l15;
            const float bias = bptr[g & 511];
#pragma unroll
            for (int r = 0; r < 4; r++) {
                const int R = rowbase + m * 16 + lhi * 4 + r;   // = b*T + t
                const int t = R & (Tt - 1), bb = R >> 9;
                xproj[((long)t * Bb + bb) * 2048 + g] = (__bf16)(acc[m][n][r] + bias);
            }
        }
}

// ---------------- recurrence: 8 wgs/dir x 512 thr, per-wave flags ------------
__global__ __launch_bounds__(512, 2) void k_rec(
    const float* __restrict__ Wf, const float* __restrict__ Wi,
    const float* __restrict__ Wo, const float* __restrict__ Wc,
    const float* __restrict__ bc0,
    const __bf16* __restrict__ xproj,
    __bf16* __restrict__ hs,           // [2][T][B][H]
    const __bf16* __restrict__ hinit,  // [2][B][H]
    int* flags)                        // [2][64]  (8 wg x 8 waves)
{
    const int dir  = blockIdx.x >> 3;
    const int gsel = blockIdx.x & 7;        // owns h-cols [gsel*64, +64)
    const int tid  = threadIdx.x;
    const int wave = tid >> 6;              // 0..7
    const int lane = tid & 63;
    const int l15  = lane & 15, lhi = lane >> 4;
    const int g    = wave >> 1;             // gate (f,i,o,c)
    const int ch   = wave & 1;              // col half (32)

    __shared__ __bf16 hlds[Bb * Hh];        // 32 KiB, XOR-swizzled h_{t-1}
    __shared__ float  gbuf[Bb * 256];       // 32 KiB, XOR-swizzled gate preacts

    // persistent B fragments: wave (g,ch) holds gate g, cols gsel*64+ch*32..+32
    const float* Wp = (g == 0) ? Wf : (g == 1) ? Wi : (g == 2) ? Wo : Wc;
    bf16x8 bfrag[2][16];
#pragma unroll
    for (int n = 0; n < 2; n++)
#pragma unroll
        for (int kk = 0; kk < 16; kk++) {
            const int row = gsel * 64 + ch * 32 + n * 16 + l15;
            bfrag[n][kk] = f32x8_to_bf16(Wp + (long)row * 768 + Ii + kk * 32 + lhi * 8);
        }

    // elementwise ownership: 4 adjacent cols of one batch row
    const int b_ew = tid & 31;
    const int c4   = (tid >> 5) * 4;        // 0..60
    float cs[4];
#pragma unroll
    for (int j = 0; j < 4; j++)
        cs[j] = (dir == 0) ? 0.f : bc0[gsel * 64 + c4 + j];

    int* flagd = flags + dir * 64;
    __bf16* hsd = hs + (long)dir * Tt * Bb * Hh;
    char* lbase = reinterpret_cast<char*>(hlds);
    char* gbase = reinterpret_cast<char*>(gbuf);

    for (int s = 0; s < Tt; ++s) {
        const int t = (dir == 0) ? s : (Tt - 1 - s);

        // prefetch this step's xproj gates (cached loads, overlap the barrier)
        const __bf16* xp = xproj + ((long)t * Bb + b_ew) * 2048 + gsel * 64 + c4;
        uint2 xr[4];
#pragma unroll
        for (int g2 = 0; g2 < 4; g2++)
            xr[g2] = *reinterpret_cast<const uint2*>(xp + g2 * 512);

        // wave 0 polls all 64 producer flags (one per (wg,wave)), bounded spin
        if (s > 0 && wave == 0) {
            for (int p = 0; p < 4096; ++p) {
                const int f = __hip_atomic_load(flagd + lane, __ATOMIC_RELAXED,
                                                __HIP_MEMORY_SCOPE_AGENT);
                if (__all(f >= s)) break;
                __builtin_amdgcn_s_sleep(1);
            }
        }
        __syncthreads();

        // stage h_{s-1} -> LDS (coherent loads; rows wave, wave+8, +16, +24)
        const __bf16* hp = (s == 0) ? (hinit + (long)dir * Bb * Hh)
                                    : (hsd + (long)((dir == 0) ? (t - 1) : (t + 1)) * Bb * Hh);
        const char* gb0 = reinterpret_cast<const char*>(hp) + wave * 1024 + lane * 16;
        f32x4 v0, v1, v2, v3;
        asm volatile("global_load_dwordx4 %0, %1, off sc0 sc1" : "=&v"(v0) : "v"(gb0) : "memory");
        asm volatile("global_load_dwordx4 %0, %1, off sc0 sc1" : "=&v"(v1) : "v"(gb0 + 8192) : "memory");
        asm volatile("global_load_dwordx4 %0, %1, off sc0 sc1" : "=&v"(v2) : "v"(gb0 + 16384) : "memory");
        asm volatile("global_load_dwordx4 %0, %1, off sc0 sc1" : "=&v"(v3) : "v"(gb0 + 24576) : "memory");
        asm volatile("s_waitcnt vmcnt(0)" ::: "memory");
        __builtin_amdgcn_sched_barrier(0);
        {
            const int r0 = wave, r1 = wave + 8, r2 = wave + 16, r3 = wave + 24;
            *reinterpret_cast<f32x4*>(lbase + r0 * 1024 + ((lane * 16) ^ ((r0 & 7) << 4))) = v0;
            *reinterpret_cast<f32x4*>(lbase + r1 * 1024 + ((lane * 16) ^ ((r1 & 7) << 4))) = v1;
            *reinterpret_cast<f32x4*>(lbase + r2 * 1024 + ((lane * 16) ^ ((r2 & 7) << 4))) = v2;
            *reinterpret_cast<f32x4*>(lbase + r3 * 1024 + ((lane * 16) ^ ((r3 & 7) << 4))) = v3;
        }
        __syncthreads();

        // this wave's slice: [32 x 512] @ [512 x 32]
        f32x4 acc[2][2];
#pragma unroll
        for (int m = 0; m < 2; m++)
#pragma unroll
            for (int n = 0; n < 2; n++) acc[m][n] = f32x4{0.f, 0.f, 0.f, 0.f};
#pragma unroll
        for (int kk = 0; kk < 16; ++kk) {
            const int kb = kk * 64 + lhi * 16;
            const int r0 = l15, r1 = 16 + l15;
            bf16x8 a0 = *reinterpret_cast<const bf16x8*>(
                lbase + r0 * 1024 + (kb ^ ((r0 & 7) << 4)));
            bf16x8 a1 = *reinterpret_cast<const bf16x8*>(
                lbase + r1 * 1024 + (kb ^ ((r1 & 7) << 4)));
            acc[0][0] = __builtin_amdgcn_mfma_f32_16x16x32_bf16(a0, bfrag[0][kk], acc[0][0], 0, 0, 0);
            acc[0][1] = __builtin_amdgcn_mfma_f32_16x16x32_bf16(a0, bfrag[1][kk], acc[0][1], 0, 0, 0);
            acc[1][0] = __builtin_amdgcn_mfma_f32_16x16x32_bf16(a1, bfrag[0][kk], acc[1][0], 0, 0, 0);
            acc[1][1] = __builtin_amdgcn_mfma_f32_16x16x32_bf16(a1, bfrag[1][kk], acc[1][1], 0, 0, 0);
        }
        // scatter to gbuf (row=batch, col = gate*64 + local col, 16B-slot XOR)
#pragma unroll
        for (int m = 0; m < 2; m++)
#pragma unroll
            for (int n = 0; n < 2; n++)
#pragma unroll
                for (int r = 0; r < 4; r++) {
                    const int row = m * 16 + lhi * 4 + r;
                    const int col = g * 64 + ch * 32 + n * 16 + l15;
                    *reinterpret_cast<float*>(
                        gbase + row * 1024 + ((col * 4) ^ ((row & 7) << 4))) = acc[m][n][r];
                }
        __syncthreads();

        // elementwise LSTM cell: 4 cols of batch row b_ew
        f32x4 G[4];
#pragma unroll
        for (int g2 = 0; g2 < 4; g2++)
            G[g2] = *reinterpret_cast<const f32x4*>(
                gbase + b_ew * 1024 + (((g2 * 64 + c4) * 4) ^ ((b_ew & 7) << 4)));
        float hv[4];
#pragma unroll
        for (int j = 0; j < 4; j++) {
            const float gf = bsel(xr[0], j) + G[0][j];
            const float gi = bsel(xr[1], j) + G[1][j];
            const float go = bsel(xr[2], j) + G[2][j];
            const float gc = bsel(xr[3], j) + G[3][j];
            const float ff = sigm(gf), ii2 = sigm(gi), oo2 = sigm(go);
            cs[j] = ff * cs[j] + ii2 * tanh_fast(gc);
            hv[j] = oo2 * tanh_fast(cs[j]);
        }
        const unsigned long long pk =
            ((unsigned long long)(((unsigned)bfbits(hv[3]) << 16) | bfbits(hv[2])) << 32) |
            (((unsigned)bfbits(hv[1]) << 16) | bfbits(hv[0]));
        char* dst = reinterpret_cast<char*>(hsd + ((long)t * Bb + b_ew) * Hh + gsel * 64 + c4);
        asm volatile("global_store_dwordx2 %0, %1, off sc0 sc1"
                     :: "v"(dst), "v"(pk) : "memory");
        asm volatile("s_waitcnt vmcnt(0)" ::: "memory");   // this wave's h at LLC
        if (lane == 0)
            __hip_atomic_store(flagd + gsel * 8 + wave, s + 1, __ATOMIC_RELAXED,
                               __HIP_MEMORY_SCOPE_AGENT);
        // no trailing barrier: next loop's poll-sync orders gbuf/hlds reuse
    }
}

// ---------------- out = cat(hf,hb) @ out_w^T + out_b -> [B][T][O] fp32 -------
__global__ __launch_bounds__(256) void k_out(
    const __bf16* __restrict__ hs,
    const float* __restrict__ out_w,
    const float* __restrict__ out_b,
    float* __restrict__ out)
{
    const int wgM = blockIdx.x;            // 0..255 (64 hs-rows each)
    const int tid = threadIdx.x;
    const int wave = tid >> 6, lane = tid & 63;
    const int mw = wave >> 1, nw = wave & 1;
    const int l15 = lane & 15, lhi = lane >> 4;

    f32x4 acc[2][4];
#pragma unroll
    for (int m = 0; m < 2; m++)
#pragma unroll
        for (int n = 0; n < 4; n++) acc[m][n] = f32x4{0.f, 0.f, 0.f, 0.f};

    const int rowbase = wgM * 64 + mw * 32;   // hs row = t*B + b
    const int colbase = nw * 64;

#pragma unroll 4
    for (int kk = 0; kk < 32; ++kk) {
        const int k0 = kk * 32 + lhi * 8;     // 0..1023
        const int d = k0 >> 9, hk = k0 & 511;
        bf16x8 a[2], b[4];
#pragma unroll
        for (int m = 0; m < 2; m++) {
            const int R = rowbase + m * 16 + l15;
            a[m] = *reinterpret_cast<const bf16x8*>(hs + ((long)d * 16384 + R) * 512 + hk);
        }
#pragma unroll
        for (int n = 0; n < 4; n++) {
            const int o = colbase + n * 16 + l15;
            b[n] = f32x8_to_bf16(out_w + (long)o * 1024 + k0);
        }
#pragma unroll
        for (int m = 0; m < 2; m++)
#pragma unroll
            for (int n = 0; n < 4; n++)
                acc[m][n] = __builtin_amdgcn_mfma_f32_16x16x32_bf16(a[m], b[n], acc[m][n], 0, 0, 0);
    }

#pragma unroll
    for (int m = 0; m < 2; m++)
#pragma unroll
        for (int n = 0; n < 4; n++) {
            const int o = colbase + n * 16 + l15;
            const float bias = out_b[o];
#pragma unroll
            for (int r = 0; r < 4; r++) {
                const int R = rowbase + m * 16 + lhi * 4 + r;   // t*32 + b
                const int tt = R >> 5, bb = R & 31;
                out[((long)bb * Tt + tt) * Oo + o] = acc[m][n][r] + bias;
            }
        }
}

// ---------------- launcher ---------------------------------------------------
extern "C" void kernel_launch(void* const* d_in, const int* in_sizes, int n_in,
                              void* d_out, int out_size, void* d_ws, size_t ws_size,
                              hipStream_t stream) {
    (void)in_sizes; (void)n_in; (void)out_size; (void)ws_size;
    const float* x    = (const float*)d_in[0];
    const float* Wf_w = (const float*)d_in[1];
    const float* Wf_b = (const float*)d_in[2];
    const float* Wi_w = (const float*)d_in[3];
    const float* Wi_b = (const float*)d_in[4];
    const float* Wo_w = (const float*)d_in[5];
    const float* Wo_b = (const float*)d_in[6];
    const float* Wc_w = (const float*)d_in[7];
    const float* Wc_b = (const float*)d_in[8];
    const float* out_w = (const float*)d_in[9];
    const float* out_b = (const float*)d_in[10];
    const float* bh0  = (const float*)d_in[11];
    const float* bc0  = (const float*)d_in[12];

    char* ws = (char*)d_ws;
    __bf16* xproj = (__bf16*)(ws);                       // 67108864 B
    __bf16* hs    = (__bf16*)(ws + 67108864);            // 33554432 B
    __bf16* hinit = (__bf16*)(ws + 100663296);           // 65536 B
    int*    flags = (int*)   (ws + 100728832);           // 512 B

    k_setup<<<64, 256, 0, stream>>>(bh0, hinit, flags);
    dim3 g1(256, 16);
    k_xproj<<<g1, 256, 0, stream>>>(x, Wf_w, Wf_b, Wi_w, Wi_b, Wo_w, Wo_b, Wc_w, Wc_b, xproj);
    k_rec<<<2 * NG, 512, 0, stream>>>(Wf_w, Wi_w, Wo_w, Wc_w, bc0, xproj, hs, hinit, flags);
    k_out<<<256, 256, 0, stream>>>(hs, out_w, out_b, (float*)d_out);
}

// Round 5
// 3436.604 us; speedup vs baseline: 1.0469x; 1.0469x over previous
//
#include <hip/hip_runtime.h>
#include <hip/hip_bf16.h>

#define Bb 32
#define Tt 512
#define Ii 256
#define Hh 512
#define Oo 128
#define NG 16   // workgroups per direction in recurrence

using bf16x8 = __attribute__((ext_vector_type(8))) __bf16;
using f32x4  = __attribute__((ext_vector_type(4))) float;

__device__ __forceinline__ bf16x8 f32x8_to_bf16(const float* p) {
    const float4 u = *reinterpret_cast<const float4*>(p);
    const float4 v = *reinterpret_cast<const float4*>(p + 4);
    bf16x8 r;
    r[0] = (__bf16)u.x; r[1] = (__bf16)u.y; r[2] = (__bf16)u.z; r[3] = (__bf16)u.w;
    r[4] = (__bf16)v.x; r[5] = (__bf16)v.y; r[6] = (__bf16)v.z; r[7] = (__bf16)v.w;
    return r;
}

__device__ __forceinline__ float sigm(float x) { return 1.f / (1.f + __expf(-x)); }
// tanh(x) = 1 - 2/(e^{2x}+1); saturates correctly for large |x|
__device__ __forceinline__ float tanh_fast(float x) {
    const float e = __expf(2.f * x);
    return 1.f - 2.f / (e + 1.f);
}
__device__ __forceinline__ unsigned short bfbits(float x) {
    return __builtin_bit_cast(unsigned short, (__bf16)x);
}

// ---------------- setup: zero flags, build initial h (fwd=0, bwd=bh0) -------
__global__ void k_setup(const float* __restrict__ bh0,
                        __bf16* __restrict__ hinit, int* __restrict__ flags) {
    const int tid = blockIdx.x * 256 + threadIdx.x;
    if (tid < 256) flags[tid] = 0;
    if (tid < Bb * Hh) {
        hinit[tid] = (__bf16)0.f;
        hinit[Bb * Hh + tid] = (__bf16)bh0[tid & (Hh - 1)];
    }
}

// ---------------- one-time Wh f32 -> bf16, layout [4][512][512] --------------
__global__ __launch_bounds__(256) void k_wcvt(
    const float* __restrict__ Wf, const float* __restrict__ Wi,
    const float* __restrict__ Wo, const float* __restrict__ Wc,
    __bf16* __restrict__ Whb)
{
    const int e = (blockIdx.x * 256 + threadIdx.x) * 4;   // 4 elems/thread
    const int g = e >> 18;
    const int rem = e & 262143;
    const int hr = rem >> 9;            // gate row (h col)
    const int k  = rem & 511;           // recurrent k
    const float* W = (g == 0) ? Wf : (g == 1) ? Wi : (g == 2) ? Wo : Wc;
    const float4 v = *reinterpret_cast<const float4*>(W + (long)hr * 768 + Ii + k);
    unsigned short s0 = bfbits(v.x), s1 = bfbits(v.y), s2 = bfbits(v.z), s3 = bfbits(v.w);
    uint2 pk;
    pk.x = ((unsigned)s1 << 16) | s0;
    pk.y = ((unsigned)s3 << 16) | s2;
    *reinterpret_cast<uint2*>(Whb + e) = pk;
}

// ---------------- xproj = x @ Wx^T + b  -> [T][B][4H] bf16 -------------------
__global__ __launch_bounds__(256) void k_xproj(
    const float* __restrict__ x,
    const float* __restrict__ Wf, const float* __restrict__ bf_,
    const float* __restrict__ Wi, const float* __restrict__ bi_,
    const float* __restrict__ Wo, const float* __restrict__ bo_,
    const float* __restrict__ Wc, const float* __restrict__ bc_,
    __bf16* __restrict__ xproj)
{
    const int wgM = blockIdx.x;           // 0..255  (64 rows each)
    const int wgN = blockIdx.y;           // 0..15   (128 cols each)
    const int tid = threadIdx.x;
    const int wave = tid >> 6, lane = tid & 63;
    const int mw = wave >> 1, nw = wave & 1;
    const int l15 = lane & 15, lhi = lane >> 4;

    const int gamma = wgN >> 2;           // whole wg in one gate (128 | 512)
    const float* W    = (gamma == 0) ? Wf : (gamma == 1) ? Wi : (gamma == 2) ? Wo : Wc;
    const float* bptr = (gamma == 0) ? bf_ : (gamma == 1) ? bi_ : (gamma == 2) ? bo_ : bc_;

    f32x4 acc[2][4];
#pragma unroll
    for (int m = 0; m < 2; m++)
#pragma unroll
        for (int n = 0; n < 4; n++) acc[m][n] = f32x4{0.f, 0.f, 0.f, 0.f};

    const int rowbase = wgM * 64 + mw * 32;
    const int colbase = wgN * 128 + nw * 64;

#pragma unroll
    for (int kk = 0; kk < 8; ++kk) {
        const int k0 = kk * 32 + lhi * 8;
        bf16x8 a[2], b[4];
#pragma unroll
        for (int m = 0; m < 2; m++) {
            const int r = rowbase + m * 16 + l15;        // x row = b*T + t
            a[m] = f32x8_to_bf16(x + (long)r * Ii + k0);
        }
#pragma unroll
        for (int n = 0; n < 4; n++) {
            const int g = colbase + n * 16 + l15;
            b[n] = f32x8_to_bf16(W + (long)(g & 511) * 768 + k0);
        }
#pragma unroll
        for (int m = 0; m < 2; m++)
#pragma unroll
            for (int n = 0; n < 4; n++)
                acc[m][n] = __builtin_amdgcn_mfma_f32_16x16x32_bf16(a[m], b[n], acc[m][n], 0, 0, 0);
    }

#pragma unroll
    for (int m = 0; m < 2; m++)
#pragma unroll
        for (int n = 0; n < 4; n++) {
            const int g = colbase + n * 16 + l15;
            const float bias = bptr[g & 511];
#pragma unroll
            for (int r = 0; r < 4; r++) {
                const int R = rowbase + m * 16 + lhi * 4 + r;   // = b*T + t
                const int t = R & (Tt - 1), bb = R >> 9;
                xproj[((long)t * Bb + bb) * 2048 + g] = (__bf16)(acc[m][n][r] + bias);
            }
        }
}

// ---------------- recurrence: 16 wgs/dir x 512 thr, resident weights ---------
__global__ __launch_bounds__(512, 1) void k_rec(
    const __bf16* __restrict__ Whb,    // [4][512][512] bf16
    const float* __restrict__ bc0,
    const __bf16* __restrict__ xproj,
    __bf16* __restrict__ hs,           // [2][T][B][H]
    const __bf16* __restrict__ hinit,  // [2][B][H]
    int* flags)                        // [2][128]  (16 wg x 8 waves)
{
    const int dir  = blockIdx.x >> 4;
    const int gsel = blockIdx.x & 15;       // owns h-cols [gsel*32, +32)
    const int tid  = threadIdx.x;
    const int wave = tid >> 6;              // 0..7
    const int lane = tid & 63;
    const int l15  = lane & 15, lhi = lane >> 4;
    const int g    = wave >> 1;             // gate (f,i,o,c)
    const int ch   = wave & 1;              // col half (16)

    __shared__ __bf16 hlds[Bb * Hh];        // 32 KiB, XOR-swizzled h_{t-1}
    __shared__ float  gbuf[Bb][130];        // 16.25 KiB, padded gate preacts

    // persistent B fragments: wave (g,ch) = gate g, cols gsel*32+ch*16..+16
    const __bf16* Wb = Whb + ((long)(g * 512 + gsel * 32 + ch * 16 + l15) * 512);
    bf16x8 bfrag[16];
#pragma unroll
    for (int kk = 0; kk < 16; kk++)
        bfrag[kk] = *reinterpret_cast<const bf16x8*>(Wb + kk * 32 + lhi * 8);

    // elementwise ownership: 2 adjacent cols of one batch row
    const int b_ew = tid & 31;
    const int c2   = (tid >> 5) * 2;        // 0..30
    float cs0 = (dir == 0) ? 0.f : bc0[gsel * 32 + c2];
    float cs1 = (dir == 0) ? 0.f : bc0[gsel * 32 + c2 + 1];

    int* flagd = flags + dir * 128;
    __bf16* hsd = hs + (long)dir * Tt * Bb * Hh;
    char* lbase = reinterpret_cast<char*>(hlds);

    for (int s = 0; s < Tt; ++s) {
        const int t = (dir == 0) ? s : (Tt - 1 - s);

        // prefetch this step's xproj gates (cached loads, overlap the barrier)
        const __bf16* xp = xproj + ((long)t * Bb + b_ew) * 2048 + gsel * 32 + c2;
        unsigned xr[4];
#pragma unroll
        for (int g2 = 0; g2 < 4; g2++)
            xr[g2] = *reinterpret_cast<const unsigned*>(xp + g2 * 512);

        // wave 0 polls all 128 producer flags, bounded spin
        if (s > 0 && wave == 0) {
            for (int p = 0; p < 4096; ++p) {
                const int f0 = __hip_atomic_load(flagd + lane, __ATOMIC_RELAXED,
                                                 __HIP_MEMORY_SCOPE_AGENT);
                const int f1 = __hip_atomic_load(flagd + 64 + lane, __ATOMIC_RELAXED,
                                                 __HIP_MEMORY_SCOPE_AGENT);
                if (__all(f0 >= s && f1 >= s)) break;
                __builtin_amdgcn_s_sleep(1);
            }
        }
        __syncthreads();

        // stage h_{s-1} -> LDS (coherent loads; rows wave, wave+8, +16, +24)
        const __bf16* hp = (s == 0) ? (hinit + (long)dir * Bb * Hh)
                                    : (hsd + (long)((dir == 0) ? (t - 1) : (t + 1)) * Bb * Hh);
        const char* gb0 = reinterpret_cast<const char*>(hp) + wave * 1024 + lane * 16;
        f32x4 v0, v1, v2, v3;
        asm volatile("global_load_dwordx4 %0, %1, off sc0 sc1" : "=&v"(v0) : "v"(gb0) : "memory");
        asm volatile("global_load_dwordx4 %0, %1, off sc0 sc1" : "=&v"(v1) : "v"(gb0 + 8192) : "memory");
        asm volatile("global_load_dwordx4 %0, %1, off sc0 sc1" : "=&v"(v2) : "v"(gb0 + 16384) : "memory");
        asm volatile("global_load_dwordx4 %0, %1, off sc0 sc1" : "=&v"(v3) : "v"(gb0 + 24576) : "memory");
        asm volatile("s_waitcnt vmcnt(0)" ::: "memory");
        __builtin_amdgcn_sched_barrier(0);
        {
            const int r0 = wave, r1 = wave + 8, r2 = wave + 16, r3 = wave + 24;
            *reinterpret_cast<f32x4*>(lbase + r0 * 1024 + ((lane * 16) ^ ((r0 & 7) << 4))) = v0;
            *reinterpret_cast<f32x4*>(lbase + r1 * 1024 + ((lane * 16) ^ ((r1 & 7) << 4))) = v1;
            *reinterpret_cast<f32x4*>(lbase + r2 * 1024 + ((lane * 16) ^ ((r2 & 7) << 4))) = v2;
            *reinterpret_cast<f32x4*>(lbase + r3 * 1024 + ((lane * 16) ^ ((r3 & 7) << 4))) = v3;
        }
        __syncthreads();

        // this wave's slice: [32 x 512] @ [512 x 16]
        f32x4 acc0 = f32x4{0.f, 0.f, 0.f, 0.f};
        f32x4 acc1 = f32x4{0.f, 0.f, 0.f, 0.f};
#pragma unroll
        for (int kk = 0; kk < 16; ++kk) {
            const int kb = kk * 64 + lhi * 16;
            const int r0 = l15, r1 = 16 + l15;
            bf16x8 a0 = *reinterpret_cast<const bf16x8*>(
                lbase + r0 * 1024 + (kb ^ ((r0 & 7) << 4)));
            bf16x8 a1 = *reinterpret_cast<const bf16x8*>(
                lbase + r1 * 1024 + (kb ^ ((r1 & 7) << 4)));
            acc0 = __builtin_amdgcn_mfma_f32_16x16x32_bf16(a0, bfrag[kk], acc0, 0, 0, 0);
            acc1 = __builtin_amdgcn_mfma_f32_16x16x32_bf16(a1, bfrag[kk], acc1, 0, 0, 0);
        }
        // scatter to gbuf: row = batch, col = g*32 + ch*16 + l15
        {
            const int col = g * 32 + ch * 16 + l15;
#pragma unroll
            for (int r = 0; r < 4; ++r) {
                gbuf[lhi * 4 + r][col]      = acc0[r];
                gbuf[16 + lhi * 4 + r][col] = acc1[r];
            }
        }
        __syncthreads();

        // elementwise LSTM cell: 2 adjacent cols of batch row b_ew
        float hv0, hv1;
        {
            const float gf = __builtin_bit_cast(float, xr[0] << 16) + gbuf[b_ew][c2];
            const float gi = __builtin_bit_cast(float, xr[1] << 16) + gbuf[b_ew][32 + c2];
            const float go = __builtin_bit_cast(float, xr[2] << 16) + gbuf[b_ew][64 + c2];
            const float gc = __builtin_bit_cast(float, xr[3] << 16) + gbuf[b_ew][96 + c2];
            const float ff = sigm(gf), ii = sigm(gi), oo = sigm(go);
            cs0 = ff * cs0 + ii * tanh_fast(gc);
            hv0 = oo * tanh_fast(cs0);
        }
        {
            const float gf = __builtin_bit_cast(float, xr[0] & 0xffff0000u) + gbuf[b_ew][c2 + 1];
            const float gi = __builtin_bit_cast(float, xr[1] & 0xffff0000u) + gbuf[b_ew][32 + c2 + 1];
            const float go = __builtin_bit_cast(float, xr[2] & 0xffff0000u) + gbuf[b_ew][64 + c2 + 1];
            const float gc = __builtin_bit_cast(float, xr[3] & 0xffff0000u) + gbuf[b_ew][96 + c2 + 1];
            const float ff = sigm(gf), ii = sigm(gi), oo = sigm(go);
            cs1 = ff * cs1 + ii * tanh_fast(gc);
            hv1 = oo * tanh_fast(cs1);
        }
        const unsigned pk = ((unsigned)bfbits(hv1) << 16) | bfbits(hv0);
        char* dst = reinterpret_cast<char*>(hsd + ((long)t * Bb + b_ew) * Hh + gsel * 32 + c2);
        asm volatile("global_store_dword %0, %1, off sc0 sc1"
                     :: "v"(dst), "v"(pk) : "memory");
        asm volatile("s_waitcnt vmcnt(0)" ::: "memory");   // this wave's h at LLC
        if (lane == 0)
            __hip_atomic_store(flagd + gsel * 8 + wave, s + 1, __ATOMIC_RELAXED,
                               __HIP_MEMORY_SCOPE_AGENT);
        // no tail barrier: next iteration's poll + B1 orders LDS reuse
    }
}

// ---------------- out = cat(hf,hb) @ out_w^T + out_b -> [B][T][O] fp32 -------
__global__ __launch_bounds__(256) void k_out(
    const __bf16* __restrict__ hs,
    const float* __restrict__ out_w,
    const float* __restrict__ out_b,
    float* __restrict__ out)
{
    const int wgM = blockIdx.x;            // 0..255 (64 hs-rows each)
    const int tid = threadIdx.x;
    const int wave = tid >> 6, lane = tid & 63;
    const int mw = wave >> 1, nw = wave & 1;
    const int l15 = lane & 15, lhi = lane >> 4;

    f32x4 acc[2][4];
#pragma unroll
    for (int m = 0; m < 2; m++)
#pragma unroll
        for (int n = 0; n < 4; n++) acc[m][n] = f32x4{0.f, 0.f, 0.f, 0.f};

    const int rowbase = wgM * 64 + mw * 32;   // hs row = t*B + b
    const int colbase = nw * 64;

#pragma unroll 4
    for (int kk = 0; kk < 32; ++kk) {
        const int k0 = kk * 32 + lhi * 8;     // 0..1023
        const int d = k0 >> 9, hk = k0 & 511;
        bf16x8 a[2], b[4];
#pragma unroll
        for (int m = 0; m < 2; m++) {
            const int R = rowbase + m * 16 + l15;
            a[m] = *reinterpret_cast<const bf16x8*>(hs + ((long)d * 16384 + R) * 512 + hk);
        }
#pragma unroll
        for (int n = 0; n < 4; n++) {
            const int o = colbase + n * 16 + l15;
            b[n] = f32x8_to_bf16(out_w + (long)o * 1024 + k0);
        }
#pragma unroll
        for (int m = 0; m < 2; m++)
#pragma unroll
            for (int n = 0; n < 4; n++)
                acc[m][n] = __builtin_amdgcn_mfma_f32_16x16x32_bf16(a[m], b[n], acc[m][n], 0, 0, 0);
    }

#pragma unroll
    for (int m = 0; m < 2; m++)
#pragma unroll
        for (int n = 0; n < 4; n++) {
            const int o = colbase + n * 16 + l15;
            const float bias = out_b[o];
#pragma unroll
            for (int r = 0; r < 4; r++) {
                const int R = rowbase + m * 16 + lhi * 4 + r;   // t*32 + b
                const int tt = R >> 5, bb = R & 31;
                out[((long)bb * Tt + tt) * Oo + o] = acc[m][n][r] + bias;
            }
        }
}

// ---------------- launcher ---------------------------------------------------
extern "C" void kernel_launch(void* const* d_in, const int* in_sizes, int n_in,
                              void* d_out, int out_size, void* d_ws, size_t ws_size,
                              hipStream_t stream) {
    (void)in_sizes; (void)n_in; (void)out_size; (void)ws_size;
    const float* x    = (const float*)d_in[0];
    const float* Wf_w = (const float*)d_in[1];
    const float* Wf_b = (const float*)d_in[2];
    const float* Wi_w = (const float*)d_in[3];
    const float* Wi_b = (const float*)d_in[4];
    const float* Wo_w = (const float*)d_in[5];
    const float* Wo_b = (const float*)d_in[6];
    const float* Wc_w = (const float*)d_in[7];
    const float* Wc_b = (const float*)d_in[8];
    const float* out_w = (const float*)d_in[9];
    const float* out_b = (const float*)d_in[10];
    const float* bh0  = (const float*)d_in[11];
    const float* bc0  = (const float*)d_in[12];

    char* ws = (char*)d_ws;
    __bf16* xproj = (__bf16*)(ws);                       // 67108864 B
    __bf16* hs    = (__bf16*)(ws + 67108864);            // 33554432 B
    __bf16* hinit = (__bf16*)(ws + 100663296);           // 65536 B
    __bf16* Whb   = (__bf16*)(ws + 100728832);           // 2097152 B
    int*    flags = (int*)   (ws + 102825984);           // 1024 B

    k_setup<<<64, 256, 0, stream>>>(bh0, hinit, flags);
    k_wcvt<<<1024, 256, 0, stream>>>(Wf_w, Wi_w, Wo_w, Wc_w, Whb);
    dim3 g1(256, 16);
    k_xproj<<<g1, 256, 0, stream>>>(x, Wf_w, Wf_b, Wi_w, Wi_b, Wo_w, Wo_b, Wc_w, Wc_b, xproj);
    k_rec<<<2 * NG, 512, 0, stream>>>(Whb, bc0, xproj, hs, hinit, flags);
    k_out<<<256, 256, 0, stream>>>(hs, out_w, out_b, (float*)d_out);
}